// Round 1
// baseline (818.947 us; speedup 1.0000x reference)
//
#include <hip/hip_runtime.h>
#include <stdint.h>

#define DD 128

using f32x4  = __attribute__((ext_vector_type(4))) float;
using bf16x8 = __attribute__((ext_vector_type(8))) short;

__device__ __forceinline__ float bf2f(short u) {
  union { unsigned int i; float f; } c;
  c.i = ((unsigned int)(unsigned short)u) << 16;
  return c.f;
}
__device__ __forceinline__ short f2bf(float f) {
  union { float f; unsigned int i; } c;
  c.f = f;
  unsigned int u = c.i;
  u += 0x7fffu + ((u >> 16) & 1u);
  return (short)(u >> 16);
}

// ---------------- CSR build ----------------
__global__ __launch_bounds__(256) void k_hist(const int* __restrict__ dst, int* __restrict__ deg, int E) {
  int e = blockIdx.x * 256 + threadIdx.x;
  if (e < E) atomicAdd(&deg[dst[e]], 1);
}

__global__ __launch_bounds__(256) void k_scan1(const int* __restrict__ deg, int* __restrict__ off,
                                               int* __restrict__ totals, int n) {
  __shared__ int sm[256];
  int t = threadIdx.x;
  int i = blockIdx.x * 256 + t;
  int v = (i < n) ? deg[i] : 0;
  sm[t] = v;
  __syncthreads();
  int acc = v;
  #pragma unroll
  for (int d = 1; d < 256; d <<= 1) {
    int add = (t >= d) ? sm[t - d] : 0;
    __syncthreads();
    acc += add;
    sm[t] = acc;
    __syncthreads();
  }
  if (i < n) off[i] = acc - v;          // exclusive
  if (t == 255) totals[blockIdx.x] = acc;
}

__global__ __launch_bounds__(256) void k_scan2(const int* __restrict__ totals, int* __restrict__ boff, int nb) {
  __shared__ int sm[256];
  int t = threadIdx.x;
  int v = (t < nb) ? totals[t] : 0;
  sm[t] = v;
  __syncthreads();
  int acc = v;
  #pragma unroll
  for (int d = 1; d < 256; d <<= 1) {
    int add = (t >= d) ? sm[t - d] : 0;
    __syncthreads();
    acc += add;
    sm[t] = acc;
    __syncthreads();
  }
  boff[t] = acc - v;
}

__global__ __launch_bounds__(256) void k_scan3(int* __restrict__ off, const int* __restrict__ boff,
                                               int* __restrict__ cursor, int n) {
  int i = blockIdx.x * 256 + threadIdx.x;
  if (i < n) {
    int o = off[i] + boff[blockIdx.x];
    off[i] = o;
    cursor[i] = o;
  }
}

__global__ __launch_bounds__(256) void k_fill(const int* __restrict__ dst, int* __restrict__ cursor,
                                              int* __restrict__ list, int E) {
  int e = blockIdx.x * 256 + threadIdx.x;
  if (e < E) {
    int p = atomicAdd(&cursor[dst[e]], 1);
    list[p] = e;
  }
}

// ---------------- node-side GEMMs: Ax,Bx,Dx,Ex (bf16 out) ----------------
// tile: 64 rows x 128 cols, K=128. 4 waves, wave w owns rows w*16..w*16+15.
// LDS padded stride 136 shorts (=272B = 17*16B): b128-aligned, 2-way banks only.
__global__ __launch_bounds__(256) void k_nodegemm(
    const float* __restrict__ x,
    const float* __restrict__ WA, const float* __restrict__ bA,
    const float* __restrict__ WB, const float* __restrict__ bB,
    const float* __restrict__ WD, const float* __restrict__ bD,
    const float* __restrict__ WE, const float* __restrict__ bE,
    short* __restrict__ Axh, short* __restrict__ Bxh,
    short* __restrict__ Dxh, short* __restrict__ Exh, int n) {
  __shared__ __align__(16) short xs[64][136];
  __shared__ __align__(16) short wt[128][136];
  int t = threadIdx.x;
  int m0 = blockIdx.x * 64;

  // x tile -> LDS (rows clamped; garbage rows never stored)
  for (int i = t; i < 64 * 128; i += 256) {
    int r = i >> 7, c = i & 127;
    int gr = m0 + r;
    if (gr >= n) gr = n - 1;
    xs[r][c] = f2bf(x[(size_t)gr * DD + c]);
  }

  const float* Ws[4] = {WA, WB, WD, WE};
  const float* bs[4] = {bA, bB, bD, bE};
  short* Os[4] = {Axh, Bxh, Dxh, Exh};

  int l = t & 63, w = t >> 6, lg = l >> 4, lc = l & 15;

  #pragma unroll
  for (int wi = 0; wi < 4; ++wi) {
    __syncthreads();  // covers xs writes (wi=0) / previous MFMA reads of wt
    // W^T -> LDS: wt[c][k] = W[k][c], vectorized 8-k per thread
    {
      int c = t & 127, kb = (t >> 7) * 8;
      const float* W = Ws[wi];
      for (int p = 0; p < 8; ++p) {
        int k0 = p * 16 + kb;
        bf16x8 v;
        #pragma unroll
        for (int j = 0; j < 8; ++j) v[j] = f2bf(W[(size_t)(k0 + j) * DD + c]);
        *(bf16x8*)&wt[c][k0] = v;
      }
    }
    __syncthreads();

    f32x4 acc[8] = {};
    #pragma unroll
    for (int kk = 0; kk < 4; ++kk) {
      bf16x8 af = *(const bf16x8*)&xs[w * 16 + lc][kk * 32 + lg * 8];
      #pragma unroll
      for (int tt = 0; tt < 8; ++tt) {
        bf16x8 bfv = *(const bf16x8*)&wt[tt * 16 + lc][kk * 32 + lg * 8];
        acc[tt] = __builtin_amdgcn_mfma_f32_16x16x32_bf16(af, bfv, acc[tt], 0, 0, 0);
      }
    }
    // epilogue: +bias, store bf16
    short* O = Os[wi];
    #pragma unroll
    for (int tt = 0; tt < 8; ++tt) {
      int col = tt * 16 + lc;
      float bv = bs[wi][col];
      #pragma unroll
      for (int j = 0; j < 4; ++j) {
        int row = m0 + w * 16 + lg * 4 + j;
        if (row < n) O[(size_t)row * DD + col] = f2bf(acc[tt][j] + bv);
      }
    }
  }
}

// ---------------- edge kernel: Ce GEMM + Dx[dst]+Ex[src]+bC -> e_ij (bf16) ----------------
__global__ __launch_bounds__(256) void k_edge(
    const float* __restrict__ e, const float* __restrict__ WC, const float* __restrict__ bC,
    const int* __restrict__ srcI, const int* __restrict__ dstI,
    const short* __restrict__ Dxh, const short* __restrict__ Exh,
    short* __restrict__ eij, int Etot) {
  __shared__ __align__(16) short es[64][136];
  __shared__ __align__(16) short wt[128][136];
  int t = threadIdx.x;
  size_t m0 = (size_t)blockIdx.x * 64;

  for (int i = t; i < 64 * 128; i += 256) {
    int r = i >> 7, c = i & 127;
    size_t gr = m0 + r;
    if (gr >= (size_t)Etot) gr = Etot - 1;
    es[r][c] = f2bf(e[gr * DD + c]);
  }
  {
    int c = t & 127, kb = (t >> 7) * 8;
    for (int p = 0; p < 8; ++p) {
      int k0 = p * 16 + kb;
      bf16x8 v;
      #pragma unroll
      for (int j = 0; j < 8; ++j) v[j] = f2bf(WC[(size_t)(k0 + j) * DD + c]);
      *(bf16x8*)&wt[c][k0] = v;
    }
  }
  __syncthreads();

  int l = t & 63, w = t >> 6, lg = l >> 4, lc = l & 15;
  f32x4 acc[8] = {};
  #pragma unroll
  for (int kk = 0; kk < 4; ++kk) {
    bf16x8 af = *(const bf16x8*)&es[w * 16 + lc][kk * 32 + lg * 8];
    #pragma unroll
    for (int tt = 0; tt < 8; ++tt) {
      bf16x8 bfv = *(const bf16x8*)&wt[tt * 16 + lc][kk * 32 + lg * 8];
      acc[tt] = __builtin_amdgcn_mfma_f32_16x16x32_bf16(af, bfv, acc[tt], 0, 0, 0);
    }
  }

  float bCv[8];
  #pragma unroll
  for (int tt = 0; tt < 8; ++tt) bCv[tt] = bC[tt * 16 + lc];

  #pragma unroll
  for (int j = 0; j < 4; ++j) {
    size_t edge = m0 + w * 16 + lg * 4 + j;
    if (edge < (size_t)Etot) {
      int dn = dstI[edge], sn = srcI[edge];
      const short* dr = Dxh + (size_t)dn * DD;
      const short* sr = Exh + (size_t)sn * DD;
      #pragma unroll
      for (int tt = 0; tt < 8; ++tt) {
        int col = tt * 16 + lc;
        float v = acc[tt][j] + bCv[tt] + bf2f(dr[col]) + bf2f(sr[col]);
        eij[edge * DD + col] = f2bf(v);
      }
    }
  }
}

// ---------------- per-feature batch stats (partials) ----------------
// bf16 source, 8 features/thread via b128 loads
__global__ __launch_bounds__(256) void k_stat_bf(const short* __restrict__ src, float* __restrict__ part, int rows) {
  int t = threadIdx.x;
  int g = t & 15;    // feature group (8 cols)
  int rl = t >> 4;   // 16 row-lanes
  float s[8] = {}, q[8] = {};
  for (int r = blockIdx.x * 16 + rl; r < rows; r += gridDim.x * 16) {
    bf16x8 v = *(const bf16x8*)&src[(size_t)r * DD + g * 8];
    #pragma unroll
    for (int j = 0; j < 8; ++j) { float f = bf2f(v[j]); s[j] += f; q[j] += f * f; }
  }
  __shared__ float sm[2048], qm[2048];
  #pragma unroll
  for (int j = 0; j < 8; ++j) { sm[t * 8 + j] = s[j]; qm[t * 8 + j] = q[j]; }
  __syncthreads();
  if (t < 128) {
    int gg = t >> 3, j = t & 7;
    float a = 0.f, b = 0.f;
    #pragma unroll
    for (int r2 = 0; r2 < 16; ++r2) { a += sm[(r2 * 16 + gg) * 8 + j]; b += qm[(r2 * 16 + gg) * 8 + j]; }
    part[(size_t)blockIdx.x * 256 + t] = a;
    part[(size_t)blockIdx.x * 256 + 128 + t] = b;
  }
}

// f32 source, 4 features/thread via float4 loads
__global__ __launch_bounds__(256) void k_stat_f(const float* __restrict__ src, float* __restrict__ part, int rows) {
  int t = threadIdx.x;
  int g = t & 31;   // feature group (4 cols)
  int rl = t >> 5;  // 8 row-lanes
  float s[4] = {}, q[4] = {};
  for (int r = blockIdx.x * 8 + rl; r < rows; r += gridDim.x * 8) {
    float4 v = *(const float4*)&src[(size_t)r * DD + g * 4];
    float vv[4] = {v.x, v.y, v.z, v.w};
    #pragma unroll
    for (int j = 0; j < 4; ++j) { s[j] += vv[j]; q[j] += vv[j] * vv[j]; }
  }
  __shared__ float sm[1024], qm[1024];
  #pragma unroll
  for (int j = 0; j < 4; ++j) { sm[t * 4 + j] = s[j]; qm[t * 4 + j] = q[j]; }
  __syncthreads();
  if (t < 128) {
    int gg = t >> 2, j = t & 3;
    float a = 0.f, b = 0.f;
    #pragma unroll
    for (int r2 = 0; r2 < 8; ++r2) { a += sm[(r2 * 32 + gg) * 4 + j]; b += qm[(r2 * 32 + gg) * 4 + j]; }
    part[(size_t)blockIdx.x * 256 + t] = a;
    part[(size_t)blockIdx.x * 256 + 128 + t] = b;
  }
}

// reduce partials -> folded BN affine: stats[c]=scale, stats[128+c]=shift
__global__ __launch_bounds__(256) void k_reduce(const float* __restrict__ part, int nblk, float invcnt,
                                                const float* __restrict__ gamma, const float* __restrict__ beta,
                                                float* __restrict__ stats) {
  int c = blockIdx.x, t = threadIdx.x;
  float a = 0.f, b = 0.f;
  for (int k = t; k < nblk; k += 256) {
    a += part[(size_t)k * 256 + c];
    b += part[(size_t)k * 256 + 128 + c];
  }
  #pragma unroll
  for (int o = 32; o > 0; o >>= 1) { a += __shfl_down(a, o); b += __shfl_down(b, o); }
  __shared__ float ra[4], rb[4];
  int l = t & 63, w = t >> 6;
  if (l == 0) { ra[w] = a; rb[w] = b; }
  __syncthreads();
  if (t == 0) {
    a = ra[0] + ra[1] + ra[2] + ra[3];
    b = rb[0] + rb[1] + rb[2] + rb[3];
    float mean = a * invcnt;
    float var = b * invcnt - mean * mean;   // biased variance
    float istd = rsqrtf(var + 1e-5f);
    float scale = gamma[c] * istd;
    stats[c] = scale;
    stats[128 + c] = beta[c] - mean * scale;
  }
}

// ---------------- aggregation gather + x_pre ----------------
__global__ __launch_bounds__(256) void k_gather(const int* __restrict__ off, const int* __restrict__ deg,
                                                const int* __restrict__ list, const int* __restrict__ srcI,
                                                const short* __restrict__ eij, const short* __restrict__ Bxh,
                                                const short* __restrict__ Axh, float* __restrict__ outx, int n) {
  int t = threadIdx.x;
  int node = blockIdx.x * 2 + (t >> 7);
  if (node >= n) return;
  int f = t & 127;
  int start = off[node];
  int dg = deg[node];
  float num = 0.f, den = 0.f;
  for (int k = 0; k < dg; ++k) {
    int id = list[start + k];
    float v = bf2f(eij[(size_t)id * DD + f]);
    float s = 1.0f / (1.0f + __expf(-v));
    float b = bf2f(Bxh[(size_t)srcI[id] * DD + f]);
    num += s * b;
    den += s;
  }
  float aggr = num / (den + 1e-6f);
  outx[(size_t)node * DD + f] = bf2f(Axh[(size_t)node * DD + f]) + aggr;
}

// ---------------- finalize ----------------
__global__ __launch_bounds__(256) void k_xfinal(float* __restrict__ v, const float* __restrict__ st, size_t n4) {
  size_t i = (size_t)blockIdx.x * 256 + threadIdx.x;
  if (i >= n4) return;
  float4 d = *(const float4*)&v[i * 4];
  int f0 = (int)((i * 4) & 127);
  d.x = fmaxf(0.f, d.x * st[f0 + 0] + st[128 + f0 + 0]);
  d.y = fmaxf(0.f, d.y * st[f0 + 1] + st[128 + f0 + 1]);
  d.z = fmaxf(0.f, d.z * st[f0 + 2] + st[128 + f0 + 2]);
  d.w = fmaxf(0.f, d.w * st[f0 + 3] + st[128 + f0 + 3]);
  *(float4*)&v[i * 4] = d;
}

__global__ __launch_bounds__(256) void k_efinal(const short* __restrict__ eij, const float* __restrict__ st,
                                                float* __restrict__ out, size_t n8) {
  size_t i = (size_t)blockIdx.x * 256 + threadIdx.x;
  if (i >= n8) return;
  bf16x8 u = *(const bf16x8*)&eij[i * 8];
  int f0 = (int)((i * 8) & 127);
  float4 a, b;
  a.x = fmaxf(0.f, bf2f(u[0]) * st[f0 + 0] + st[128 + f0 + 0]);
  a.y = fmaxf(0.f, bf2f(u[1]) * st[f0 + 1] + st[128 + f0 + 1]);
  a.z = fmaxf(0.f, bf2f(u[2]) * st[f0 + 2] + st[128 + f0 + 2]);
  a.w = fmaxf(0.f, bf2f(u[3]) * st[f0 + 3] + st[128 + f0 + 3]);
  b.x = fmaxf(0.f, bf2f(u[4]) * st[f0 + 4] + st[128 + f0 + 4]);
  b.y = fmaxf(0.f, bf2f(u[5]) * st[f0 + 5] + st[128 + f0 + 5]);
  b.z = fmaxf(0.f, bf2f(u[6]) * st[f0 + 6] + st[128 + f0 + 6]);
  b.w = fmaxf(0.f, bf2f(u[7]) * st[f0 + 7] + st[128 + f0 + 7]);
  *(float4*)&out[i * 8] = a;
  *(float4*)&out[i * 8 + 4] = b;
}

extern "C" void kernel_launch(void* const* d_in, const int* in_sizes, int n_in,
                              void* d_out, int out_size, void* d_ws, size_t ws_size,
                              hipStream_t stream) {
  const float* x  = (const float*)d_in[0];
  const float* e  = (const float*)d_in[1];
  const int*   ei = (const int*)d_in[2];
  const float* WA = (const float*)d_in[3];  const float* bA = (const float*)d_in[4];
  const float* WB = (const float*)d_in[5];  const float* bB = (const float*)d_in[6];
  const float* WC = (const float*)d_in[7];  const float* bC = (const float*)d_in[8];
  const float* WD = (const float*)d_in[9];  const float* bD = (const float*)d_in[10];
  const float* WE = (const float*)d_in[11]; const float* bE = (const float*)d_in[12];
  const float* gx = (const float*)d_in[13]; const float* bx = (const float*)d_in[14];
  const float* ge = (const float*)d_in[15]; const float* be = (const float*)d_in[16];

  int N = in_sizes[0] / DD;
  int E = in_sizes[2] / 2;
  const int* srcI = ei;       // edge_index[0]
  const int* dstI = ei + E;   // edge_index[1]

  float* outx = (float*)d_out;
  float* oute = (float*)d_out + (size_t)N * DD;

  // workspace carve-out (256B aligned); total ~261 MB
  char* wp = (char*)d_ws;
  auto alloc = [&](size_t sz) { char* p = wp; wp += (sz + 255) & ~(size_t)255; return p; };
  short* Axh    = (short*)alloc((size_t)N * DD * 2);
  short* Bxh    = (short*)alloc((size_t)N * DD * 2);
  short* Dxh    = (short*)alloc((size_t)N * DD * 2);
  short* Exh    = (short*)alloc((size_t)N * DD * 2);
  short* eij    = (short*)alloc((size_t)E * DD * 2);
  int*   deg    = (int*)alloc((size_t)N * 4);
  int*   off    = (int*)alloc((size_t)N * 4);
  int*   cursor = (int*)alloc((size_t)N * 4);
  int*   totals = (int*)alloc(1024);
  int*   boff   = (int*)alloc(1024);
  int*   list   = (int*)alloc((size_t)E * 4);
  float* ePart  = (float*)alloc((size_t)1024 * 256 * 4);
  float* xPart  = (float*)alloc((size_t)256 * 256 * 4);
  float* statsE = (float*)alloc(1024);
  float* statsX = (float*)alloc(1024);
  (void)ws_size; (void)n_in; (void)out_size;

  int nsb = (N + 255) / 256;

  hipMemsetAsync(deg, 0, (size_t)N * 4, stream);
  k_hist<<<(E + 255) / 256, 256, 0, stream>>>(dstI, deg, E);
  k_scan1<<<nsb, 256, 0, stream>>>(deg, off, totals, N);
  k_scan2<<<1, 256, 0, stream>>>(totals, boff, nsb);
  k_scan3<<<nsb, 256, 0, stream>>>(off, boff, cursor, N);
  k_fill<<<(E + 255) / 256, 256, 0, stream>>>(dstI, cursor, list, E);

  k_nodegemm<<<(N + 63) / 64, 256, 0, stream>>>(x, WA, bA, WB, bB, WD, bD, WE, bE,
                                                Axh, Bxh, Dxh, Exh, N);
  k_edge<<<(E + 63) / 64, 256, 0, stream>>>(e, WC, bC, srcI, dstI, Dxh, Exh, eij, E);

  k_stat_bf<<<1024, 256, 0, stream>>>(eij, ePart, E);
  k_reduce<<<128, 256, 0, stream>>>(ePart, 1024, 1.0f / (float)E, ge, be, statsE);

  k_gather<<<(N + 1) / 2, 256, 0, stream>>>(off, deg, list, srcI, eij, Bxh, Axh, outx, N);
  k_stat_f<<<256, 256, 0, stream>>>(outx, xPart, N);
  k_reduce<<<128, 256, 0, stream>>>(xPart, 256, 1.0f / (float)N, gx, bx, statsX);

  k_xfinal<<<(int)(((size_t)N * DD / 4 + 255) / 256), 256, 0, stream>>>(outx, statsX, (size_t)N * DD / 4);
  k_efinal<<<(int)(((size_t)E * DD / 8 + 255) / 256), 256, 0, stream>>>(eij, statsE, oute, (size_t)E * DD / 8);
}

// Round 2
// 682.120 us; speedup vs baseline: 1.2006x; 1.2006x over previous
//
#include <hip/hip_runtime.h>
#include <stdint.h>

#define DD 128
#define NB_G 2048   // k_gather blocks (partials count)

using f32x4  = __attribute__((ext_vector_type(4))) float;
using bf16x8 = __attribute__((ext_vector_type(8))) short;

__device__ __forceinline__ float bf2f(short u) {
  union { unsigned int i; float f; } c;
  c.i = ((unsigned int)(unsigned short)u) << 16;
  return c.f;
}
__device__ __forceinline__ short f2bf(float f) {
  union { float f; unsigned int i; } c;
  c.f = f;
  unsigned int u = c.i;
  u += 0x7fffu + ((u >> 16) & 1u);
  return (short)(u >> 16);
}

// ---------------- CSR build ----------------
__global__ __launch_bounds__(256) void k_hist(const int* __restrict__ dst, int* __restrict__ deg, int E) {
  int e = blockIdx.x * 256 + threadIdx.x;
  if (e < E) atomicAdd(&deg[dst[e]], 1);
}

__global__ __launch_bounds__(256) void k_scan1(const int* __restrict__ deg, int* __restrict__ off,
                                               int* __restrict__ totals, int n) {
  __shared__ int sm[256];
  int t = threadIdx.x;
  int i = blockIdx.x * 256 + t;
  int v = (i < n) ? deg[i] : 0;
  sm[t] = v;
  __syncthreads();
  int acc = v;
  #pragma unroll
  for (int d = 1; d < 256; d <<= 1) {
    int add = (t >= d) ? sm[t - d] : 0;
    __syncthreads();
    acc += add;
    sm[t] = acc;
    __syncthreads();
  }
  if (i < n) off[i] = acc - v;          // exclusive
  if (t == 255) totals[blockIdx.x] = acc;
}

__global__ __launch_bounds__(256) void k_scan2(const int* __restrict__ totals, int* __restrict__ boff, int nb) {
  __shared__ int sm[256];
  int t = threadIdx.x;
  int v = (t < nb) ? totals[t] : 0;
  sm[t] = v;
  __syncthreads();
  int acc = v;
  #pragma unroll
  for (int d = 1; d < 256; d <<= 1) {
    int add = (t >= d) ? sm[t - d] : 0;
    __syncthreads();
    acc += add;
    sm[t] = acc;
    __syncthreads();
  }
  boff[t] = acc - v;
}

__global__ __launch_bounds__(256) void k_scan3(int* __restrict__ off, const int* __restrict__ boff,
                                               int* __restrict__ cursor, int n) {
  int i = blockIdx.x * 256 + threadIdx.x;
  if (i < n) {
    int o = off[i] + boff[blockIdx.x];
    off[i] = o;
    cursor[i] = o;
  }
}

// fill: also record permutation (posOf: edge->slot) and sorted src (srcS: slot->src node)
__global__ __launch_bounds__(256) void k_fill(const int* __restrict__ dst, const int* __restrict__ src,
                                              int* __restrict__ cursor, int* __restrict__ list,
                                              int* __restrict__ srcS, int* __restrict__ posOf, int E) {
  int e = blockIdx.x * 256 + threadIdx.x;
  if (e < E) {
    int p = atomicAdd(&cursor[dst[e]], 1);
    list[p] = e;
    srcS[p] = src[e];
    posOf[e] = p;
  }
}

// ---------------- node-side GEMMs: Ax,Bx,Dx,Ex (bf16 out) ----------------
__global__ __launch_bounds__(256) void k_nodegemm(
    const float* __restrict__ x,
    const float* __restrict__ WA, const float* __restrict__ bA,
    const float* __restrict__ WB, const float* __restrict__ bB,
    const float* __restrict__ WD, const float* __restrict__ bD,
    const float* __restrict__ WE, const float* __restrict__ bE,
    short* __restrict__ Axh, short* __restrict__ Bxh,
    short* __restrict__ Dxh, short* __restrict__ Exh, int n) {
  __shared__ __align__(16) short xs[64][136];
  __shared__ __align__(16) short wt[128][136];
  int t = threadIdx.x;
  int m0 = blockIdx.x * 64;

  for (int i = t; i < 64 * 32; i += 256) {
    int r = i >> 5, c4 = (i & 31) * 4;
    int gr = m0 + r;
    if (gr >= n) gr = n - 1;
    float4 v = *(const float4*)&x[(size_t)gr * DD + c4];
    xs[r][c4 + 0] = f2bf(v.x); xs[r][c4 + 1] = f2bf(v.y);
    xs[r][c4 + 2] = f2bf(v.z); xs[r][c4 + 3] = f2bf(v.w);
  }

  const float* Ws[4] = {WA, WB, WD, WE};
  const float* bs[4] = {bA, bB, bD, bE};
  short* Os[4] = {Axh, Bxh, Dxh, Exh};

  int l = t & 63, w = t >> 6, lg = l >> 4, lc = l & 15;

  #pragma unroll
  for (int wi = 0; wi < 4; ++wi) {
    __syncthreads();  // covers xs writes (wi=0) / previous MFMA reads of wt
    {
      int c = t & 127, kb = (t >> 7) * 8;
      const float* W = Ws[wi];
      for (int p = 0; p < 8; ++p) {
        int k0 = p * 16 + kb;
        bf16x8 v;
        #pragma unroll
        for (int j = 0; j < 8; ++j) v[j] = f2bf(W[(size_t)(k0 + j) * DD + c]);
        *(bf16x8*)&wt[c][k0] = v;
      }
    }
    __syncthreads();

    f32x4 acc[8] = {};
    #pragma unroll
    for (int kk = 0; kk < 4; ++kk) {
      bf16x8 af = *(const bf16x8*)&xs[w * 16 + lc][kk * 32 + lg * 8];
      #pragma unroll
      for (int tt = 0; tt < 8; ++tt) {
        bf16x8 bfv = *(const bf16x8*)&wt[tt * 16 + lc][kk * 32 + lg * 8];
        acc[tt] = __builtin_amdgcn_mfma_f32_16x16x32_bf16(af, bfv, acc[tt], 0, 0, 0);
      }
    }
    short* O = Os[wi];
    #pragma unroll
    for (int tt = 0; tt < 8; ++tt) {
      int col = tt * 16 + lc;
      float bv = bs[wi][col];
      #pragma unroll
      for (int j = 0; j < 4; ++j) {
        int row = m0 + w * 16 + lg * 4 + j;
        if (row < n) O[(size_t)row * DD + col] = f2bf(acc[tt][j] + bv);
      }
    }
  }
}

// ---------------- edge kernel: Ce GEMM + Dx[dst]+Ex[src]+bC -> eijS (CSR order) ----------------
__global__ __launch_bounds__(256) void k_edge(
    const float* __restrict__ e, const float* __restrict__ WC, const float* __restrict__ bC,
    const int* __restrict__ srcI, const int* __restrict__ dstI, const int* __restrict__ posOf,
    const short* __restrict__ Dxh, const short* __restrict__ Exh,
    short* __restrict__ eijS, int Etot) {
  __shared__ __align__(16) short es[64][136];
  __shared__ __align__(16) short wt[128][136];
  int t = threadIdx.x;
  size_t m0 = (size_t)blockIdx.x * 64;

  for (int i = t; i < 64 * 32; i += 256) {
    int r = i >> 5, c4 = (i & 31) * 4;
    size_t gr = m0 + r;
    if (gr >= (size_t)Etot) gr = Etot - 1;
    float4 v = *(const float4*)&e[gr * DD + c4];
    es[r][c4 + 0] = f2bf(v.x); es[r][c4 + 1] = f2bf(v.y);
    es[r][c4 + 2] = f2bf(v.z); es[r][c4 + 3] = f2bf(v.w);
  }
  {
    int c = t & 127, kb = (t >> 7) * 8;
    for (int p = 0; p < 8; ++p) {
      int k0 = p * 16 + kb;
      bf16x8 v;
      #pragma unroll
      for (int j = 0; j < 8; ++j) v[j] = f2bf(WC[(size_t)(k0 + j) * DD + c]);
      *(bf16x8*)&wt[c][k0] = v;
    }
  }
  __syncthreads();

  int l = t & 63, w = t >> 6, lg = l >> 4, lc = l & 15;
  f32x4 acc[8] = {};
  #pragma unroll
  for (int kk = 0; kk < 4; ++kk) {
    bf16x8 af = *(const bf16x8*)&es[w * 16 + lc][kk * 32 + lg * 8];
    #pragma unroll
    for (int tt = 0; tt < 8; ++tt) {
      bf16x8 bfv = *(const bf16x8*)&wt[tt * 16 + lc][kk * 32 + lg * 8];
      acc[tt] = __builtin_amdgcn_mfma_f32_16x16x32_bf16(af, bfv, acc[tt], 0, 0, 0);
    }
  }
  float bCv[8];
  #pragma unroll
  for (int tt = 0; tt < 8; ++tt) bCv[tt] = bC[tt * 16 + lc];

  __syncthreads();           // everyone done reading es/wt
  #pragma unroll
  for (int tt = 0; tt < 8; ++tt) {
    int col = tt * 16 + lc;
    #pragma unroll
    for (int j = 0; j < 4; ++j)
      es[w * 16 + lg * 4 + j][col] = f2bf(acc[tt][j] + bCv[tt]);
  }
  __syncthreads();

  // v = Ce+bC (restaged) + Dx[dst] + Ex[src]; scatter row to CSR slot
  int rr = t >> 4, cl = (t & 15) * 8;
  #pragma unroll
  for (int p = 0; p < 4; ++p) {
    int r = rr + p * 16;
    size_t edge = m0 + r;
    if (edge < (size_t)Etot) {
      int dn = dstI[edge], sn = srcI[edge], pos = posOf[edge];
      bf16x8 cv = *(const bf16x8*)&es[r][cl];
      bf16x8 dv = *(const bf16x8*)&Dxh[(size_t)dn * DD + cl];
      bf16x8 sv = *(const bf16x8*)&Exh[(size_t)sn * DD + cl];
      bf16x8 o;
      #pragma unroll
      for (int j = 0; j < 8; ++j) o[j] = f2bf(bf2f(cv[j]) + bf2f(dv[j]) + bf2f(sv[j]));
      *(bf16x8*)&eijS[(size_t)pos * DD + cl] = o;
    }
  }
}

// ---------------- gather (streaming, wave-per-node) + fused stats ----------------
__global__ __launch_bounds__(256) void k_gather(
    const int* __restrict__ off, const int* __restrict__ deg, const int* __restrict__ srcS,
    const short* __restrict__ eijS, const short* __restrict__ Bxh, const short* __restrict__ Axh,
    float* __restrict__ outx, float* __restrict__ pE, float* __restrict__ pX, int n) {
  int t = threadIdx.x;
  int w = t >> 6, l = t & 63;
  int qw = l >> 4, fi = l & 15;
  int waveId = blockIdx.x * 4 + w;
  const int nwaves = NB_G * 4;

  float se[8] = {}, qe[8] = {};
  float sx[4] = {}, qx[4] = {};

  for (int node = waveId; node < n; node += nwaves) {
    int start = off[node], dg = deg[node];
    float num[8] = {}, den[8] = {};
    int k = qw;
    // 2x unrolled: 8 independent load chains per wave
    for (; k + 4 < dg; k += 8) {
      int p0 = start + k, p1 = start + k + 4;
      int s0 = srcS[p0], s1 = srcS[p1];
      bf16x8 e0 = *(const bf16x8*)&eijS[(size_t)p0 * DD + fi * 8];
      bf16x8 e1 = *(const bf16x8*)&eijS[(size_t)p1 * DD + fi * 8];
      bf16x8 b0 = *(const bf16x8*)&Bxh[(size_t)s0 * DD + fi * 8];
      bf16x8 b1 = *(const bf16x8*)&Bxh[(size_t)s1 * DD + fi * 8];
      #pragma unroll
      for (int j = 0; j < 8; ++j) {
        float v0 = bf2f(e0[j]), v1 = bf2f(e1[j]);
        float g0 = 1.f / (1.f + __expf(-v0)), g1 = 1.f / (1.f + __expf(-v1));
        num[j] += g0 * bf2f(b0[j]) + g1 * bf2f(b1[j]);
        den[j] += g0 + g1;
        se[j] += v0 + v1; qe[j] += v0 * v0 + v1 * v1;
      }
    }
    for (; k < dg; k += 4) {
      int p0 = start + k;
      int s0 = srcS[p0];
      bf16x8 e0 = *(const bf16x8*)&eijS[(size_t)p0 * DD + fi * 8];
      bf16x8 b0 = *(const bf16x8*)&Bxh[(size_t)s0 * DD + fi * 8];
      #pragma unroll
      for (int j = 0; j < 8; ++j) {
        float v0 = bf2f(e0[j]);
        float g0 = 1.f / (1.f + __expf(-v0));
        num[j] += g0 * bf2f(b0[j]);
        den[j] += g0;
        se[j] += v0; qe[j] += v0 * v0;
      }
    }
    // reduce num/den across quarter-waves
    #pragma unroll
    for (int j = 0; j < 8; ++j) {
      num[j] += __shfl_xor(num[j], 16); num[j] += __shfl_xor(num[j], 32);
      den[j] += __shfl_xor(den[j], 16); den[j] += __shfl_xor(den[j], 32);
    }
    if (qw < 2) {  // lane(qw,fi) writes cols fi*8+qw*4 .. +3
      int c0 = fi * 8 + qw * 4;
      short4 ax = *(const short4*)&Axh[(size_t)node * DD + c0];
      short axa[4] = {ax.x, ax.y, ax.z, ax.w};
      float4 o;
      float vv[4];
      #pragma unroll
      for (int j = 0; j < 4; ++j) {
        int jj = qw * 4 + j;
        float aggr = num[jj] / (den[jj] + 1e-6f);
        float xp = bf2f(axa[j]) + aggr;
        vv[j] = xp;
        sx[j] += xp; qx[j] += xp * xp;
      }
      o.x = vv[0]; o.y = vv[1]; o.z = vv[2]; o.w = vv[3];
      *(float4*)&outx[(size_t)node * DD + c0] = o;
    }
  }

  // block-level stat partials
  #pragma unroll
  for (int j = 0; j < 8; ++j) {
    se[j] += __shfl_xor(se[j], 16); se[j] += __shfl_xor(se[j], 32);
    qe[j] += __shfl_xor(qe[j], 16); qe[j] += __shfl_xor(qe[j], 32);
  }
  __shared__ float lsE[4][128], lqE[4][128], lsX[4][128], lqX[4][128];
  if (qw == 0) {
    #pragma unroll
    for (int j = 0; j < 8; ++j) { lsE[w][fi * 8 + j] = se[j]; lqE[w][fi * 8 + j] = qe[j]; }
  }
  if (qw < 2) {
    #pragma unroll
    for (int j = 0; j < 4; ++j) { lsX[w][fi * 8 + qw * 4 + j] = sx[j]; lqX[w][fi * 8 + qw * 4 + j] = qx[j]; }
  }
  __syncthreads();
  if (t < 128) {
    float a = lsE[0][t] + lsE[1][t] + lsE[2][t] + lsE[3][t];
    float b = lqE[0][t] + lqE[1][t] + lqE[2][t] + lqE[3][t];
    pE[(size_t)blockIdx.x * 256 + t] = a;
    pE[(size_t)blockIdx.x * 256 + 128 + t] = b;
  } else {
    int c = t - 128;
    float a = lsX[0][c] + lsX[1][c] + lsX[2][c] + lsX[3][c];
    float b = lqX[0][c] + lqX[1][c] + lqX[2][c] + lqX[3][c];
    pX[(size_t)blockIdx.x * 256 + c] = a;
    pX[(size_t)blockIdx.x * 256 + 128 + c] = b;
  }
}

// reduce partials -> folded BN affine: stats[c]=scale, stats[128+c]=shift
__global__ __launch_bounds__(256) void k_reduce(const float* __restrict__ part, int nblk, float invcnt,
                                                const float* __restrict__ gamma, const float* __restrict__ beta,
                                                float* __restrict__ stats) {
  int c = blockIdx.x, t = threadIdx.x;
  float a = 0.f, b = 0.f;
  for (int k = t; k < nblk; k += 256) {
    a += part[(size_t)k * 256 + c];
    b += part[(size_t)k * 256 + 128 + c];
  }
  #pragma unroll
  for (int o = 32; o > 0; o >>= 1) { a += __shfl_down(a, o); b += __shfl_down(b, o); }
  __shared__ float ra[4], rb[4];
  int l = t & 63, w = t >> 6;
  if (l == 0) { ra[w] = a; rb[w] = b; }
  __syncthreads();
  if (t == 0) {
    a = ra[0] + ra[1] + ra[2] + ra[3];
    b = rb[0] + rb[1] + rb[2] + rb[3];
    float mean = a * invcnt;
    float var = b * invcnt - mean * mean;   // biased variance
    float istd = rsqrtf(var + 1e-5f);
    float scale = gamma[c] * istd;
    stats[c] = scale;
    stats[128 + c] = beta[c] - mean * scale;
  }
}

// ---------------- finalize ----------------
__global__ __launch_bounds__(256) void k_xfinal(float* __restrict__ v, const float* __restrict__ st, size_t n4) {
  size_t i = (size_t)blockIdx.x * 256 + threadIdx.x;
  if (i >= n4) return;
  float4 d = *(const float4*)&v[i * 4];
  int f0 = (int)((i * 4) & 127);
  d.x = fmaxf(0.f, d.x * st[f0 + 0] + st[128 + f0 + 0]);
  d.y = fmaxf(0.f, d.y * st[f0 + 1] + st[128 + f0 + 1]);
  d.z = fmaxf(0.f, d.z * st[f0 + 2] + st[128 + f0 + 2]);
  d.w = fmaxf(0.f, d.w * st[f0 + 3] + st[128 + f0 + 3]);
  *(float4*)&v[i * 4] = d;
}

// read eijS sequentially, BN+ReLU, scatter rows back to original edge order
__global__ __launch_bounds__(256) void k_efinal(const short* __restrict__ eijS, const int* __restrict__ list,
                                                const float* __restrict__ st, float* __restrict__ out, int E) {
  int t = threadIdx.x;
  int pos = blockIdx.x * 16 + (t >> 4);
  if (pos >= E) return;
  int cl = (t & 15) * 8;
  int row = list[pos];
  bf16x8 u = *(const bf16x8*)&eijS[(size_t)pos * DD + cl];
  float4 s0 = *(const float4*)&st[cl], s1 = *(const float4*)&st[cl + 4];
  float4 h0 = *(const float4*)&st[128 + cl], h1 = *(const float4*)&st[128 + cl + 4];
  float4 a, b;
  a.x = fmaxf(0.f, bf2f(u[0]) * s0.x + h0.x);
  a.y = fmaxf(0.f, bf2f(u[1]) * s0.y + h0.y);
  a.z = fmaxf(0.f, bf2f(u[2]) * s0.z + h0.z);
  a.w = fmaxf(0.f, bf2f(u[3]) * s0.w + h0.w);
  b.x = fmaxf(0.f, bf2f(u[4]) * s1.x + h1.x);
  b.y = fmaxf(0.f, bf2f(u[5]) * s1.y + h1.y);
  b.z = fmaxf(0.f, bf2f(u[6]) * s1.z + h1.z);
  b.w = fmaxf(0.f, bf2f(u[7]) * s1.w + h1.w);
  *(float4*)&out[(size_t)row * DD + cl] = a;
  *(float4*)&out[(size_t)row * DD + cl + 4] = b;
}

extern "C" void kernel_launch(void* const* d_in, const int* in_sizes, int n_in,
                              void* d_out, int out_size, void* d_ws, size_t ws_size,
                              hipStream_t stream) {
  const float* x  = (const float*)d_in[0];
  const float* e  = (const float*)d_in[1];
  const int*   ei = (const int*)d_in[2];
  const float* WA = (const float*)d_in[3];  const float* bA = (const float*)d_in[4];
  const float* WB = (const float*)d_in[5];  const float* bB = (const float*)d_in[6];
  const float* WC = (const float*)d_in[7];  const float* bC = (const float*)d_in[8];
  const float* WD = (const float*)d_in[9];  const float* bD = (const float*)d_in[10];
  const float* WE = (const float*)d_in[11]; const float* bE = (const float*)d_in[12];
  const float* gx = (const float*)d_in[13]; const float* bx = (const float*)d_in[14];
  const float* ge = (const float*)d_in[15]; const float* be = (const float*)d_in[16];

  int N = in_sizes[0] / DD;
  int E = in_sizes[2] / 2;
  const int* srcI = ei;       // edge_index[0]
  const int* dstI = ei + E;   // edge_index[1]

  float* outx = (float*)d_out;
  float* oute = (float*)d_out + (size_t)N * DD;

  char* wp = (char*)d_ws;
  auto alloc = [&](size_t sz) { char* p = wp; wp += (sz + 255) & ~(size_t)255; return p; };
  short* Axh    = (short*)alloc((size_t)N * DD * 2);
  short* Bxh    = (short*)alloc((size_t)N * DD * 2);
  short* Dxh    = (short*)alloc((size_t)N * DD * 2);
  short* Exh    = (short*)alloc((size_t)N * DD * 2);
  short* eijS   = (short*)alloc((size_t)E * DD * 2);
  int*   deg    = (int*)alloc((size_t)N * 4);
  int*   off    = (int*)alloc((size_t)N * 4);
  int*   cursor = (int*)alloc((size_t)N * 4);
  int*   totals = (int*)alloc(1024);
  int*   boff   = (int*)alloc(1024);
  int*   list   = (int*)alloc((size_t)E * 4);
  int*   srcS   = (int*)alloc((size_t)E * 4);
  int*   posOf  = (int*)alloc((size_t)E * 4);
  float* pE     = (float*)alloc((size_t)NB_G * 256 * 4);
  float* pX     = (float*)alloc((size_t)NB_G * 256 * 4);
  float* statsE = (float*)alloc(1024);
  float* statsX = (float*)alloc(1024);
  (void)ws_size; (void)n_in; (void)out_size;

  int nsb = (N + 255) / 256;

  hipMemsetAsync(deg, 0, (size_t)N * 4, stream);
  k_hist<<<(E + 255) / 256, 256, 0, stream>>>(dstI, deg, E);
  k_scan1<<<nsb, 256, 0, stream>>>(deg, off, totals, N);
  k_scan2<<<1, 256, 0, stream>>>(totals, boff, nsb);
  k_scan3<<<nsb, 256, 0, stream>>>(off, boff, cursor, N);
  k_fill<<<(E + 255) / 256, 256, 0, stream>>>(dstI, srcI, cursor, list, srcS, posOf, E);

  k_nodegemm<<<(N + 63) / 64, 256, 0, stream>>>(x, WA, bA, WB, bB, WD, bD, WE, bE,
                                                Axh, Bxh, Dxh, Exh, N);
  k_edge<<<(E + 63) / 64, 256, 0, stream>>>(e, WC, bC, srcI, dstI, posOf, Dxh, Exh, eijS, E);

  k_gather<<<NB_G, 256, 0, stream>>>(off, deg, srcS, eijS, Bxh, Axh, outx, pE, pX, N);
  k_reduce<<<128, 256, 0, stream>>>(pE, NB_G, 1.0f / (float)E, ge, be, statsE);
  k_reduce<<<128, 256, 0, stream>>>(pX, NB_G, 1.0f / (float)N, gx, bx, statsX);

  k_xfinal<<<(int)(((size_t)N * DD / 4 + 255) / 256), 256, 0, stream>>>(outx, statsX, (size_t)N * DD / 4);
  k_efinal<<<(E + 15) / 16, 256, 0, stream>>>(eijS, list, statsE, oute, E);
}